// Round 5
// baseline (1374.769 us; speedup 1.0000x reference)
//
#include <hip/hip_runtime.h>
#include <math.h>

#define HW    9216
#define HDIM  96
#define WDIM  96
#define NIMG  8
#define CF    64
#define OFFCH 144
#define MSKCH 72

typedef unsigned short u16;
typedef unsigned int   u32;
typedef _Float16 f16;
typedef __attribute__((ext_vector_type(8))) _Float16 f16x8;
typedef __attribute__((ext_vector_type(4))) float f32x4;
typedef __attribute__((ext_vector_type(4))) u32 u32x4;

// ---- fp16 hi/scaled-lo helpers ---------------------------------------------
// v ~= hi + lo/2048, hi = fp16(v), lo = fp16((v-hi)*2048).
__device__ inline u16 f16b(f16 h){ u16 r; __builtin_memcpy(&r, &h, 2); return r; }
__device__ inline f16 b16f(u16 b){ f16 h; __builtin_memcpy(&h, &b, 2); return h; }
__device__ inline void split16(float v, u16& hb, u16& lb){
    f16 h = (f16)v;
    f16 l = (f16)((v - (float)h) * 2048.0f);
    hb = f16b(h); lb = f16b(l);
}

// ---- weight prepack ---------------------------------------------------------
// wp (u16): bneck hi [64*9*128] @0, lo @73728;
//           layer i: hi [224*9*64] @147456+i*258048, lo @+129024 (oc>=216 zeroed)
// dwp (f32): deform weights transposed [layer][g][k][c][o]
__global__ void pack_w_k(const float* __restrict__ bw,
                         const float* __restrict__ ow0, const float* __restrict__ ow1,
                         const float* __restrict__ ow2, const float* __restrict__ ow3,
                         const float* __restrict__ dw0, const float* __restrict__ dw1,
                         const float* __restrict__ dw2, const float* __restrict__ dw3,
                         u16* __restrict__ wp, float* __restrict__ dwp)
{
    const float* ows[4] = {ow0, ow1, ow2, ow3};
    const float* dws[4] = {dw0, dw1, dw2, dw3};
    int total = 73728 + 4 * 124416;
    for (int j = blockIdx.x * blockDim.x + threadIdx.x; j < total;
         j += gridDim.x * blockDim.x) {
        if (j < 73728) {                      // bneck src [oc][ci][tap]
            int oc = j / 1152, r = j % 1152, ci = r / 9, tap = r % 9;
            u16 h, l; split16(bw[j], h, l);
            size_t dst = (size_t)(oc * 9 + tap) * 128 + ci;
            wp[dst] = h; wp[73728 + dst] = l;
        } else {
            int k = j - 73728;
            int layer = k / 124416, r = k % 124416;
            int oc = r / 576, r3 = r % 576, ci = r3 / 9, tap = r3 % 9;
            u16 h, l; split16(ows[layer][r], h, l);
            size_t dst = 147456 + (size_t)layer * 258048 + (size_t)(oc * 9 + tap) * 64 + ci;
            wp[dst] = h; wp[dst + 129024] = l;
        }
    }
    for (int j = blockIdx.x * blockDim.x + threadIdx.x; j < 4 * 4608;
         j += gridDim.x * blockDim.x) {
        int layer = j / 4608, e = j % 4608;
        size_t base = 147456 + (size_t)layer * 258048;
        wp[base + 124416 + e] = 0;
        wp[base + 129024 + 124416 + e] = 0;
    }
    for (int j = blockIdx.x * blockDim.x + threadIdx.x; j < 4 * 8 * 576;
         j += gridDim.x * blockDim.x) {
        int layer = j / 4608, r = j % 4608, g = r / 576, e = r % 576;
        int kk = e / 64, c = (e / 8) % 8, o = e % 8;
        dwp[j] = dws[layer][(size_t)(g * 8 + o) * 72 + c * 9 + kk];
    }
}

// ---- concat(burst[n], burst[0]) -> NHWC fp16 hi/lo [8][9216][128] -----------
// LDS-transpose: coalesced NCHW float4 reads -> per-pixel 64B h + 64B l stores.
__global__ __launch_bounds__(256) void prep_cat_k(
    const float* __restrict__ burst, u16* __restrict__ ch, u16* __restrict__ cl)
{
    __shared__ float tb[32 * 257];
    const int id = blockIdx.x;
    const int n = id & 7, w = id >> 3;          // image-per-XCD
    const int pix0 = w * 256;
    const int tid = threadIdx.x;

    for (int pass = 0; pass < 4; ++pass) {
        const float* src = (pass < 2) ? burst + (size_t)n * CF * HW : burst;
        const int chb = (pass & 1) * 32;
        __syncthreads();
        {
            int c = tid >> 3, q = tid & 7;
            const float* sp = src + (size_t)(chb + c) * HW + pix0;
#pragma unroll
            for (int j = 0; j < 8; ++j) {
                int px = q * 4 + j * 32;
                f32x4 v = *(const f32x4*)(sp + px);
                tb[c * 257 + px + 0] = v.x;
                tb[c * 257 + px + 1] = v.y;
                tb[c * 257 + px + 2] = v.z;
                tb[c * 257 + px + 3] = v.w;
            }
        }
        __syncthreads();
        {
            int px = tid;
            size_t base = ((size_t)n * HW + pix0 + px) * 128 + pass * 32;
#pragma unroll
            for (int cq = 0; cq < 4; ++cq) {
                u32 hw_[4], lw_[4];
#pragma unroll
                for (int e = 0; e < 4; ++e) {
                    int c0 = cq * 8 + e * 2;
                    u16 h0, l0, h1, l1;
                    split16(tb[c0 * 257 + px], h0, l0);
                    split16(tb[(c0 + 1) * 257 + px], h1, l1);
                    hw_[e] = (u32)h0 | ((u32)h1 << 16);
                    lw_[e] = (u32)l0 | ((u32)l1 << 16);
                }
                u32x4 hv = {hw_[0], hw_[1], hw_[2], hw_[3]};
                u32x4 lv = {lw_[0], lw_[1], lw_[2], lw_[3]};
                *(u32x4*)(ch + base + cq * 8) = hv;
                *(u32x4*)(cl + base + cq * 8) = lv;
            }
        }
    }
}

// ---- MFMA implicit-GEMM conv3x3 (fp16 hi/scaled-lo, dual accumulators) ------
// 1D grid, image-per-XCD swizzle: n=id&7, w=id>>3, tile=w%36, ocg=w/36.
// MODE 0: feat NHWC h/l out. MODE 1: tile-blocked offs fp32 + mask fp16 via
// LDS-transpose epilogue with nontemporal stores.
template<int CIN, int MODE>
__global__ __launch_bounds__(256, 3) void conv_mfma_k(
    const u16* __restrict__ in_hi, const u16* __restrict__ in_lo,
    const u16* __restrict__ w_hi,  const u16* __restrict__ w_lo,
    float* __restrict__ offs_out,  u16* __restrict__ mask_out,
    u16* __restrict__ out_hi,      u16* __restrict__ out_lo)
{
    __shared__ __align__(16) u16 lds[25920];        // hi @0, lo @12960
    u16* lds_hi = lds;
    u16* lds_lo = lds + 12960;

    const int id = blockIdx.x;
    const int n = id & 7, w = id >> 3;
    const int tile = w % 36, ocg = w / 36;
    const int tid = threadIdx.x;
    const int wv = tid >> 6, lane = tid & 63;
    const int lx = lane & 15, lg = lane >> 4;
    const int oy = (tile / 6) * 16, ox = (tile % 6) * 16;

    f32x4 acc1[2][4], acc2[2][4];
#pragma unroll
    for (int t = 0; t < 2; ++t)
#pragma unroll
        for (int r = 0; r < 4; ++r) {
            acc1[t][r] = (f32x4){0.f, 0.f, 0.f, 0.f};
            acc2[t][r] = (f32x4){0.f, 0.f, 0.f, 0.f};
        }

    for (int chk = 0; chk < CIN / 32; ++chk) {
        __syncthreads();
        for (int u = tid; u < 2592; u += 256) {
            int q = u & 3, half = (u >> 2) & 1, pos = u >> 3;
            int yy = pos / 18, xx = pos - yy * 18;
            int gy = oy + yy - 1, gx = ox + xx - 1;
            u32x4 val = {0u, 0u, 0u, 0u};
            if (gy >= 0 && gy < HDIM && gx >= 0 && gx < WDIM) {
                const u16* src = (half ? in_lo : in_hi) +
                    ((size_t)(n * HW + gy * WDIM + gx) * CIN + chk * 32 + q * 8);
                val = *(const u32x4*)src;
            }
            u16* dst = (half ? lds_lo : lds_hi) + pos * 40 + q * 8;
            *(u32x4*)dst = val;
        }
        __syncthreads();

        for (int tap = 0; tap < 9; ++tap) {
            int ky = tap / 3, kx = tap - ky * 3;
            f16x8 ah[2], al[2];
#pragma unroll
            for (int t = 0; t < 2; ++t) {
                int oc = ocg * 32 + t * 16 + lx;
                size_t idx = ((size_t)(oc * 9 + tap) * CIN) + chk * 32 + lg * 8;
                ah[t] = *(const f16x8*)(w_hi + idx);
                al[t] = *(const f16x8*)(w_lo + idx);
            }
            f16x8 bh[4], bl[4];
#pragma unroll
            for (int r = 0; r < 4; ++r) {
                int py = wv * 4 + r;
                int off = ((py + ky) * 18 + (lx + kx)) * 40 + lg * 8;
                bh[r] = *(const f16x8*)(lds_hi + off);
                bl[r] = *(const f16x8*)(lds_lo + off);
            }
#pragma unroll
            for (int t = 0; t < 2; ++t)
#pragma unroll
                for (int r = 0; r < 4; ++r) {
                    acc1[t][r] = __builtin_amdgcn_mfma_f32_16x16x32_f16(ah[t], bh[r], acc1[t][r], 0, 0, 0);
                    acc2[t][r] = __builtin_amdgcn_mfma_f32_16x16x32_f16(ah[t], bl[r], acc2[t][r], 0, 0, 0);
                    acc2[t][r] = __builtin_amdgcn_mfma_f32_16x16x32_f16(al[t], bh[r], acc2[t][r], 0, 0, 0);
                }
        }
    }

    if (MODE == 0) {
        // feat NHWC h/l (same-tile blocks share an XCD -> L2 write-combine ok)
#pragma unroll
        for (int t = 0; t < 2; ++t)
#pragma unroll
            for (int r = 0; r < 4; ++r) {
                int y = oy + wv * 4 + r;
                int pix = y * WDIM + ox + lx;
                u16 h[4], l[4];
#pragma unroll
                for (int v = 0; v < 4; ++v) {
                    float val = acc1[t][r][v] + acc2[t][r][v] * (1.0f / 2048.0f);
                    split16(val, h[v], l[v]);
                }
                size_t b = ((size_t)(n * HW + pix)) * CF + ocg * 32 + t * 16 + lg * 4;
                uint2 hv, lv;
                hv.x = (u32)h[0] | ((u32)h[1] << 16); hv.y = (u32)h[2] | ((u32)h[3] << 16);
                lv.x = (u32)l[0] | ((u32)l[1] << 16); lv.y = (u32)l[2] | ((u32)l[3] << 16);
                *(uint2*)(out_hi + b) = hv;
                *(uint2*)(out_lo + b) = lv;
            }
    } else {
        // LDS-transpose epilogue -> dense tile-blocked stores
        __syncthreads();
        float* tb = (float*)lds;                 // 32 x 257 fp32 (32.9 KB)
#pragma unroll
        for (int t = 0; t < 2; ++t)
#pragma unroll
            for (int r = 0; r < 4; ++r) {
                int px = (wv * 4 + r) * 16 + lx;
#pragma unroll
                for (int v = 0; v < 4; ++v) {
                    int ocl = t * 16 + lg * 4 + v;
                    tb[ocl * 257 + px] = acc1[t][r][v] + acc2[t][r][v] * (1.0f / 2048.0f);
                }
            }
        __syncthreads();

        const int ocl = tid >> 3;                // 0..31
        const int px0 = (tid & 7) * 32;
        const int glob = ocg * 32 + ocl;
        const float* row = tb + ocl * 257 + px0;
        if (glob < OFFCH) {
            float* dst = offs_out + (((size_t)n * 36 + tile) * OFFCH + glob) * 256 + px0;
#pragma unroll
            for (int j = 0; j < 8; ++j) {
                f32x4 v4 = {row[4*j], row[4*j+1], row[4*j+2], row[4*j+3]};
                __builtin_nontemporal_store(v4, (f32x4*)(dst + 4 * j));
            }
        } else if (glob < OFFCH + MSKCH) {
            u16* dst = mask_out + (((size_t)n * 36 + tile) * MSKCH + (glob - OFFCH)) * 256 + px0;
#pragma unroll
            for (int j = 0; j < 4; ++j) {
                u32 wd[4];
#pragma unroll
                for (int e = 0; e < 4; ++e) {
                    float a = row[8*j + 2*e],   sa = 1.f / (1.f + __expf(-a));
                    float b = row[8*j + 2*e+1], sb = 1.f / (1.f + __expf(-b));
                    wd[e] = (u32)f16b((f16)sa) | ((u32)f16b((f16)sb) << 16);
                }
                u32x4 m4 = {wd[0], wd[1], wd[2], wd[3]};
                __builtin_nontemporal_store(m4, (u32x4*)(dst + 8 * j));
            }
        }
    }
}

// ---- modulated deformable conv; blocked offs/mask, fp16-hi feat gathers -----
template<int LAST>
__global__ __launch_bounds__(256, 4) void deform_k(
    const u16* __restrict__ fh,   const float* __restrict__ offs,
    const u16* __restrict__ mask, const float* __restrict__ wgtp, // [g][k][c][o]
    const float* __restrict__ bias,
    u16* __restrict__ out_h, u16* __restrict__ out_l, float* __restrict__ out32)
{
    const int id = blockIdx.x;
    const int n = id & 7, w = id >> 3;
    const int tile = w % 36, g = w / 36;

    const int ty = threadIdx.x >> 4, tx = threadIdx.x & 15;
    const int h  = (tile / 6) * 16 + ty;
    const int wx = (tile % 6) * 16 + tx;
    const int pix = h * WDIM + wx;
    const int pixT = ty * 16 + tx;

    const float* wg = wgtp + (size_t)g * 576;
    const float* ob = offs + (((size_t)n * 36 + tile) * OFFCH) * 256;
    const u16*   mb = mask + (((size_t)n * 36 + tile) * MSKCH) * 256;
    const u16*   fb = fh + (size_t)n * HW * CF + g * 8;

    float acc[8];
#pragma unroll
    for (int o = 0; o < 8; ++o) acc[o] = 0.f;

#pragma unroll
    for (int k = 0; k < 9; ++k) {
        float dy = __builtin_nontemporal_load(ob + (g * 18 + 2 * k    ) * 256 + pixT);
        float dx = __builtin_nontemporal_load(ob + (g * 18 + 2 * k + 1) * 256 + pixT);
        float m  = (float)b16f(__builtin_nontemporal_load(mb + (g * 9 + k) * 256 + pixT));

        float py = dy + (float)(k / 3 - 1) + (float)h;
        float px = dx + (float)(k % 3 - 1) + (float)wx;
        float y0f = floorf(py), x0f = floorf(px);
        float ly = py - y0f, lx = px - x0f;
        int y0 = (int)y0f, x0 = (int)x0f;
        int y1 = y0 + 1,   x1 = x0 + 1;

        bool vy0 = (y0 >= 0) && (y0 < HDIM);
        bool vy1 = (y1 >= 0) && (y1 < HDIM);
        bool vx0 = (x0 >= 0) && (x0 < WDIM);
        bool vx1 = (x1 >= 0) && (x1 < WDIM);

        float w00 = (vy0 && vx0) ? (1.f - ly) * (1.f - lx) : 0.f;
        float w01 = (vy0 && vx1) ? (1.f - ly) * lx         : 0.f;
        float w10 = (vy1 && vx0) ? ly * (1.f - lx)         : 0.f;
        float w11 = (vy1 && vx1) ? ly * lx                 : 0.f;

        int y0c = min(max(y0, 0), HDIM - 1), y1c = min(max(y1, 0), HDIM - 1);
        int x0c = min(max(x0, 0), WDIM - 1), x1c = min(max(x1, 0), WDIM - 1);

        f16x8 C00 = *(const f16x8*)(fb + (size_t)(y0c * WDIM + x0c) * CF);
        f16x8 C01 = *(const f16x8*)(fb + (size_t)(y0c * WDIM + x1c) * CF);
        f16x8 C10 = *(const f16x8*)(fb + (size_t)(y1c * WDIM + x0c) * CF);
        f16x8 C11 = *(const f16x8*)(fb + (size_t)(y1c * WDIM + x1c) * CF);

#pragma unroll
        for (int c = 0; c < 8; ++c) {
            float v =      w00 * (float)C00[c];
            v = fmaf(w01, (float)C01[c], v);
            v = fmaf(w10, (float)C10[c], v);
            v = fmaf(w11, (float)C11[c], v);
            v *= m;
            const float* w8 = wg + (k * 8 + c) * 8;
#pragma unroll
            for (int o = 0; o < 8; ++o)
                acc[o] = fmaf(w8[o], v, acc[o]);
        }
    }

    if (LAST) {
#pragma unroll
        for (int o = 0; o < 8; ++o)
            out32[((size_t)n * CF + g * 8 + o) * HW + pix] = acc[o] + bias[g * 8 + o];
    } else {
        u16 hb[8], lb[8];
#pragma unroll
        for (int o = 0; o < 8; ++o)
            split16(acc[o] + bias[g * 8 + o], hb[o], lb[o]);
        size_t b = ((size_t)n * HW + pix) * CF + g * 8;
        u32x4 hv, lv;
        hv.x = (u32)hb[0] | ((u32)hb[1] << 16); hv.y = (u32)hb[2] | ((u32)hb[3] << 16);
        hv.z = (u32)hb[4] | ((u32)hb[5] << 16); hv.w = (u32)hb[6] | ((u32)hb[7] << 16);
        lv.x = (u32)lb[0] | ((u32)lb[1] << 16); lv.y = (u32)lb[2] | ((u32)lb[3] << 16);
        lv.z = (u32)lb[4] | ((u32)lb[5] << 16); lv.w = (u32)lb[6] | ((u32)lb[7] << 16);
        *(u32x4*)(out_h + b) = hv;
        *(u32x4*)(out_l + b) = lv;
    }
}

// ---------------------------------------------------------------------------
extern "C" void kernel_launch(void* const* d_in, const int* in_sizes, int n_in,
                              void* d_out, int out_size, void* d_ws, size_t ws_size,
                              hipStream_t stream) {
    const float* burst = (const float*)d_in[0];
    const float* bw    = (const float*)d_in[1];

    const float* ow[4]; const float* dw[4]; const float* db[4];
    bool interleaved = (in_sizes[3] == 64 * 8 * 9);
    for (int i = 0; i < 4; ++i) {
        if (interleaved) {
            ow[i] = (const float*)d_in[2 + 3 * i];
            dw[i] = (const float*)d_in[3 + 3 * i];
            db[i] = (const float*)d_in[4 + 3 * i];
        } else {
            ow[i] = (const float*)d_in[2 + i];
            dw[i] = (const float*)d_in[6 + i];
            db[i] = (const float*)d_in[10 + i];
        }
    }

    float* out = (float*)d_out;

    // ws layout (74.4 MB)
    float* offs    = (float*)d_ws;                   // 10,616,832 f32 (blocked)
    u16*   mask    = (u16*)(offs + 10616832);        //  5,308,416 u16 (blocked)
    u16*   featB_h = mask + 5308416;                 //  4,718,592 u16
    u16*   featB_l = featB_h + 4718592;              //  4,718,592 u16
    u16*   wp      = featB_l + 4718592;              //  1,179,648 u16
    float* dwp     = (float*)(wp + 1179648);         //     18,432 f32
    u16*   cat_h   = (u16*)d_ws;                     // alias over offs region
    u16*   cat_l   = cat_h + 9437184;
    u16*   featA_h = (u16*)d_out;                    // alias over d_out
    u16*   featA_l = featA_h + 4718592;

    const u16* wp_bh = wp;
    const u16* wp_bl = wp + 73728;
    const u16* wp_oh[4], * wp_ol[4];
    for (int i = 0; i < 4; ++i) {
        wp_oh[i] = wp + 147456 + (size_t)i * 258048;
        wp_ol[i] = wp_oh[i] + 129024;
    }

    pack_w_k<<<dim3(512), dim3(256), 0, stream>>>(
        bw, ow[0], ow[1], ow[2], ow[3], dw[0], dw[1], dw[2], dw[3], wp, dwp);
    prep_cat_k<<<dim3(288), dim3(256), 0, stream>>>(burst, cat_h, cat_l);

    // bottleneck -> featA (d_out alias). 576 = 8 img x 36 tiles x 2 ocg
    conv_mfma_k<128, 0><<<dim3(576), dim3(256), 0, stream>>>(
        cat_h, cat_l, wp_bh, wp_bl, nullptr, nullptr, featA_h, featA_l);

    // ping-pong: A -> B -> A -> B -> d_out(fp32)
    u16* fx_h = featA_h; u16* fx_l = featA_l;
    u16* fy_h = featB_h; u16* fy_l = featB_l;
    for (int i = 0; i < 4; ++i) {
        conv_mfma_k<64, 1><<<dim3(2016), dim3(256), 0, stream>>>(
            fx_h, fx_l, wp_oh[i], wp_ol[i], offs, mask, nullptr, nullptr);
        if (i < 3) {
            deform_k<0><<<dim3(2304), dim3(256), 0, stream>>>(
                fx_h, offs, mask, dwp + (size_t)i * 4608, db[i], fy_h, fy_l, nullptr);
            u16* th = fx_h; u16* tl = fx_l;
            fx_h = fy_h; fx_l = fy_l; fy_h = th; fy_l = tl;
        } else {
            deform_k<1><<<dim3(2304), dim3(256), 0, stream>>>(
                fx_h, offs, mask, dwp + (size_t)i * 4608, db[i], nullptr, nullptr, out);
        }
    }
}

// Round 6
// 822.285 us; speedup vs baseline: 1.6719x; 1.6719x over previous
//
#include <hip/hip_runtime.h>
#include <math.h>

#define HW    9216
#define HDIM  96
#define WDIM  96
#define NIMG  8
#define CF    64
#define OFFCH 144
#define MSKCH 72

typedef unsigned short u16;
typedef unsigned int   u32;
typedef _Float16 f16;
typedef __attribute__((ext_vector_type(8))) _Float16 f16x8;
typedef __attribute__((ext_vector_type(4))) float f32x4;
typedef __attribute__((ext_vector_type(4))) u32 u32x4;

// ---- fp16 hi/scaled-lo helpers ---------------------------------------------
// v ~= hi + lo/2048, hi = fp16(v), lo = fp16((v-hi)*2048).
__device__ inline u16 f16b(f16 h){ u16 r; __builtin_memcpy(&r, &h, 2); return r; }
__device__ inline f16 b16f(u16 b){ f16 h; __builtin_memcpy(&h, &b, 2); return h; }
__device__ inline void split16(float v, u16& hb, u16& lb){
    f16 h = (f16)v;
    f16 l = (f16)((v - (float)h) * 2048.0f);
    hb = f16b(h); lb = f16b(l);
}

// ---- weight prepack ---------------------------------------------------------
__global__ void pack_w_k(const float* __restrict__ bw,
                         const float* __restrict__ ow0, const float* __restrict__ ow1,
                         const float* __restrict__ ow2, const float* __restrict__ ow3,
                         const float* __restrict__ dw0, const float* __restrict__ dw1,
                         const float* __restrict__ dw2, const float* __restrict__ dw3,
                         u16* __restrict__ wp, float* __restrict__ dwp)
{
    const float* ows[4] = {ow0, ow1, ow2, ow3};
    const float* dws[4] = {dw0, dw1, dw2, dw3};
    int total = 73728 + 4 * 124416;
    for (int j = blockIdx.x * blockDim.x + threadIdx.x; j < total;
         j += gridDim.x * blockDim.x) {
        if (j < 73728) {                      // bneck src [oc][ci][tap]
            int oc = j / 1152, r = j % 1152, ci = r / 9, tap = r % 9;
            u16 h, l; split16(bw[j], h, l);
            size_t dst = (size_t)(oc * 9 + tap) * 128 + ci;
            wp[dst] = h; wp[73728 + dst] = l;
        } else {
            int k = j - 73728;
            int layer = k / 124416, r = k % 124416;
            int oc = r / 576, r3 = r % 576, ci = r3 / 9, tap = r3 % 9;
            u16 h, l; split16(ows[layer][r], h, l);
            size_t dst = 147456 + (size_t)layer * 258048 + (size_t)(oc * 9 + tap) * 64 + ci;
            wp[dst] = h; wp[dst + 129024] = l;
        }
    }
    for (int j = blockIdx.x * blockDim.x + threadIdx.x; j < 4 * 4608;
         j += gridDim.x * blockDim.x) {
        int layer = j / 4608, e = j % 4608;
        size_t base = 147456 + (size_t)layer * 258048;
        wp[base + 124416 + e] = 0;
        wp[base + 129024 + 124416 + e] = 0;
    }
    for (int j = blockIdx.x * blockDim.x + threadIdx.x; j < 4 * 8 * 576;
         j += gridDim.x * blockDim.x) {
        int layer = j / 4608, r = j % 4608, g = r / 576, e = r % 576;
        int kk = e / 64, c = (e / 8) % 8, o = e % 8;
        dwp[j] = dws[layer][(size_t)(g * 8 + o) * 72 + c * 9 + kk];
    }
}

// ---- concat(burst[n], burst[0]) -> NHWC fp16 hi/lo [8][9216][128] -----------
__global__ __launch_bounds__(256) void prep_cat_k(
    const float* __restrict__ burst, u16* __restrict__ ch, u16* __restrict__ cl)
{
    __shared__ float tb[32 * 257];
    const int id = blockIdx.x;
    const int n = id & 7, w = id >> 3;          // image-per-XCD
    const int pix0 = w * 256;
    const int tid = threadIdx.x;

    for (int pass = 0; pass < 4; ++pass) {
        const float* src = (pass < 2) ? burst + (size_t)n * CF * HW : burst;
        const int chb = (pass & 1) * 32;
        __syncthreads();
        {
            int c = tid >> 3, q = tid & 7;
            const float* sp = src + (size_t)(chb + c) * HW + pix0;
#pragma unroll
            for (int j = 0; j < 8; ++j) {
                int px = q * 4 + j * 32;
                f32x4 v = *(const f32x4*)(sp + px);
                tb[c * 257 + px + 0] = v.x;
                tb[c * 257 + px + 1] = v.y;
                tb[c * 257 + px + 2] = v.z;
                tb[c * 257 + px + 3] = v.w;
            }
        }
        __syncthreads();
        {
            int px = tid;
            size_t base = ((size_t)n * HW + pix0 + px) * 128 + pass * 32;
#pragma unroll
            for (int cq = 0; cq < 4; ++cq) {
                u32 hw_[4], lw_[4];
#pragma unroll
                for (int e = 0; e < 4; ++e) {
                    int c0 = cq * 8 + e * 2;
                    u16 h0, l0, h1, l1;
                    split16(tb[c0 * 257 + px], h0, l0);
                    split16(tb[(c0 + 1) * 257 + px], h1, l1);
                    hw_[e] = (u32)h0 | ((u32)h1 << 16);
                    lw_[e] = (u32)l0 | ((u32)l1 << 16);
                }
                u32x4 hv = {hw_[0], hw_[1], hw_[2], hw_[3]};
                u32x4 lv = {lw_[0], lw_[1], lw_[2], lw_[3]};
                *(u32x4*)(ch + base + cq * 8) = hv;
                *(u32x4*)(cl + base + cq * 8) = lv;
            }
        }
    }
}

// ---- MFMA implicit-GEMM conv3x3 (fp16 hi/scaled-lo, dual accumulators) ------
// 1D grid, image-per-XCD swizzle: n=id&7, w=id>>3. Tile-major block order
// (ocg fastest) so same-tile blocks run adjacently on one XCD -> halo L2 hits.
// MODE 0: feat NHWC h/l out. MODE 1: tile-blocked offs fp32 + mask fp16,
// lane-contiguous stores (no nontemporal).
template<int CIN, int MODE>
__global__ __launch_bounds__(256, 3) void conv_mfma_k(
    const u16* __restrict__ in_hi, const u16* __restrict__ in_lo,
    const u16* __restrict__ w_hi,  const u16* __restrict__ w_lo,
    float* __restrict__ offs_out,  u16* __restrict__ mask_out,
    u16* __restrict__ out_hi,      u16* __restrict__ out_lo)
{
    __shared__ __align__(16) u16 lds[25920];        // hi @0, lo @12960
    u16* lds_hi = lds;
    u16* lds_lo = lds + 12960;

    const int id = blockIdx.x;
    const int n = id & 7, w = id >> 3;
    const int tile = (MODE == 0) ? (w >> 1) : (w / 7);
    const int ocg  = (MODE == 0) ? (w & 1)  : (w % 7);
    const int tid = threadIdx.x;
    const int wv = tid >> 6, lane = tid & 63;
    const int lx = lane & 15, lg = lane >> 4;
    const int oy = (tile / 6) * 16, ox = (tile % 6) * 16;

    f32x4 acc1[2][4], acc2[2][4];
#pragma unroll
    for (int t = 0; t < 2; ++t)
#pragma unroll
        for (int r = 0; r < 4; ++r) {
            acc1[t][r] = (f32x4){0.f, 0.f, 0.f, 0.f};
            acc2[t][r] = (f32x4){0.f, 0.f, 0.f, 0.f};
        }

    for (int chk = 0; chk < CIN / 32; ++chk) {
        __syncthreads();
        for (int u = tid; u < 2592; u += 256) {
            int q = u & 3, half = (u >> 2) & 1, pos = u >> 3;
            int yy = pos / 18, xx = pos - yy * 18;
            int gy = oy + yy - 1, gx = ox + xx - 1;
            u32x4 val = {0u, 0u, 0u, 0u};
            if (gy >= 0 && gy < HDIM && gx >= 0 && gx < WDIM) {
                const u16* src = (half ? in_lo : in_hi) +
                    ((size_t)(n * HW + gy * WDIM + gx) * CIN + chk * 32 + q * 8);
                val = *(const u32x4*)src;
            }
            u16* dst = (half ? lds_lo : lds_hi) + pos * 40 + q * 8;
            *(u32x4*)dst = val;
        }
        __syncthreads();

        for (int tap = 0; tap < 9; ++tap) {
            int ky = tap / 3, kx = tap - ky * 3;
            f16x8 ah[2], al[2];
#pragma unroll
            for (int t = 0; t < 2; ++t) {
                int oc = ocg * 32 + t * 16 + lx;
                size_t idx = ((size_t)(oc * 9 + tap) * CIN) + chk * 32 + lg * 8;
                ah[t] = *(const f16x8*)(w_hi + idx);
                al[t] = *(const f16x8*)(w_lo + idx);
            }
            f16x8 bh[4], bl[4];
#pragma unroll
            for (int r = 0; r < 4; ++r) {
                int py = wv * 4 + r;
                int off = ((py + ky) * 18 + (lx + kx)) * 40 + lg * 8;
                bh[r] = *(const f16x8*)(lds_hi + off);
                bl[r] = *(const f16x8*)(lds_lo + off);
            }
#pragma unroll
            for (int t = 0; t < 2; ++t)
#pragma unroll
                for (int r = 0; r < 4; ++r) {
                    acc1[t][r] = __builtin_amdgcn_mfma_f32_16x16x32_f16(ah[t], bh[r], acc1[t][r], 0, 0, 0);
                    acc2[t][r] = __builtin_amdgcn_mfma_f32_16x16x32_f16(ah[t], bl[r], acc2[t][r], 0, 0, 0);
                    acc2[t][r] = __builtin_amdgcn_mfma_f32_16x16x32_f16(al[t], bh[r], acc2[t][r], 0, 0, 0);
                }
        }
    }

    if (MODE == 0) {
#pragma unroll
        for (int t = 0; t < 2; ++t)
#pragma unroll
            for (int r = 0; r < 4; ++r) {
                int y = oy + wv * 4 + r;
                int pix = y * WDIM + ox + lx;
                u16 h[4], l[4];
#pragma unroll
                for (int v = 0; v < 4; ++v) {
                    float val = acc1[t][r][v] + acc2[t][r][v] * (1.0f / 2048.0f);
                    split16(val, h[v], l[v]);
                }
                size_t b = ((size_t)(n * HW + pix)) * CF + ocg * 32 + t * 16 + lg * 4;
                uint2 hv, lv;
                hv.x = (u32)h[0] | ((u32)h[1] << 16); hv.y = (u32)h[2] | ((u32)h[3] << 16);
                lv.x = (u32)l[0] | ((u32)l[1] << 16); lv.y = (u32)l[2] | ((u32)l[3] << 16);
                *(uint2*)(out_hi + b) = hv;
                *(uint2*)(out_lo + b) = lv;
            }
    } else {
        // LDS-transpose epilogue -> dense tile-blocked, lane-contiguous stores
        __syncthreads();
        float* tb = (float*)lds;                 // 32 x 257 fp32 (32.9 KB)
#pragma unroll
        for (int t = 0; t < 2; ++t)
#pragma unroll
            for (int r = 0; r < 4; ++r) {
                int px = (wv * 4 + r) * 16 + lx;
#pragma unroll
                for (int v = 0; v < 4; ++v) {
                    int ocl = t * 16 + lg * 4 + v;
                    tb[ocl * 257 + px] = acc1[t][r][v] + acc2[t][r][v] * (1.0f / 2048.0f);
                }
            }
        __syncthreads();

        const int ocl = tid >> 3;                // 0..31
        const int q   = tid & 7;                 // 0..7
        const int glob = ocg * 32 + ocl;
        const float* row = tb + ocl * 257;
        if (glob < OFFCH) {
            float* dst = offs_out + (((size_t)n * 36 + tile) * OFFCH + glob) * 256;
#pragma unroll
            for (int j = 0; j < 8; ++j) {
                int px = q * 4 + j * 32;         // lanes 0..7 contiguous 128B
                f32x4 v4 = {row[px], row[px+1], row[px+2], row[px+3]};
                *(f32x4*)(dst + px) = v4;
            }
        } else if (glob < OFFCH + MSKCH) {
            u16* dst = mask_out + (((size_t)n * 36 + tile) * MSKCH + (glob - OFFCH)) * 256;
#pragma unroll
            for (int j = 0; j < 4; ++j) {
                int px = q * 8 + j * 64;         // lanes 0..7 contiguous 128B
                u32 wd[4];
#pragma unroll
                for (int e = 0; e < 4; ++e) {
                    float a = row[px + 2*e],     sa = 1.f / (1.f + __expf(-a));
                    float b = row[px + 2*e + 1], sb = 1.f / (1.f + __expf(-b));
                    wd[e] = (u32)f16b((f16)sa) | ((u32)f16b((f16)sb) << 16);
                }
                u32x4 m4 = {wd[0], wd[1], wd[2], wd[3]};
                *(u32x4*)(dst + px) = m4;
            }
        }
    }
}

// ---- modulated deformable conv; blocked offs/mask, fp16-hi feat gathers -----
// Tile-major order (g fastest): the 8 g-blocks of a tile share feat lines.
template<int LAST>
__global__ __launch_bounds__(256, 4) void deform_k(
    const u16* __restrict__ fh,   const float* __restrict__ offs,
    const u16* __restrict__ mask, const float* __restrict__ wgtp, // [g][k][c][o]
    const float* __restrict__ bias,
    u16* __restrict__ out_h, u16* __restrict__ out_l, float* __restrict__ out32)
{
    const int id = blockIdx.x;
    const int n = id & 7, w = id >> 3;
    const int tile = w >> 3, g = w & 7;

    const int ty = threadIdx.x >> 4, tx = threadIdx.x & 15;
    const int h  = (tile / 6) * 16 + ty;
    const int wx = (tile % 6) * 16 + tx;
    const int pix = h * WDIM + wx;
    const int pixT = ty * 16 + tx;

    const float* wg = wgtp + (size_t)g * 576;
    const float* ob = offs + (((size_t)n * 36 + tile) * OFFCH) * 256;
    const u16*   mb = mask + (((size_t)n * 36 + tile) * MSKCH) * 256;
    const u16*   fb = fh + (size_t)n * HW * CF + g * 8;

    float acc[8];
#pragma unroll
    for (int o = 0; o < 8; ++o) acc[o] = 0.f;

#pragma unroll
    for (int k = 0; k < 9; ++k) {
        float dy = ob[(g * 18 + 2 * k    ) * 256 + pixT];
        float dx = ob[(g * 18 + 2 * k + 1) * 256 + pixT];
        float m  = (float)b16f(mb[(g * 9 + k) * 256 + pixT]);

        float py = dy + (float)(k / 3 - 1) + (float)h;
        float px = dx + (float)(k % 3 - 1) + (float)wx;
        float y0f = floorf(py), x0f = floorf(px);
        float ly = py - y0f, lx = px - x0f;
        int y0 = (int)y0f, x0 = (int)x0f;
        int y1 = y0 + 1,   x1 = x0 + 1;

        bool vy0 = (y0 >= 0) && (y0 < HDIM);
        bool vy1 = (y1 >= 0) && (y1 < HDIM);
        bool vx0 = (x0 >= 0) && (x0 < WDIM);
        bool vx1 = (x1 >= 0) && (x1 < WDIM);

        float w00 = (vy0 && vx0) ? (1.f - ly) * (1.f - lx) : 0.f;
        float w01 = (vy0 && vx1) ? (1.f - ly) * lx         : 0.f;
        float w10 = (vy1 && vx0) ? ly * (1.f - lx)         : 0.f;
        float w11 = (vy1 && vx1) ? ly * lx                 : 0.f;

        int y0c = min(max(y0, 0), HDIM - 1), y1c = min(max(y1, 0), HDIM - 1);
        int x0c = min(max(x0, 0), WDIM - 1), x1c = min(max(x1, 0), WDIM - 1);

        f16x8 C00 = *(const f16x8*)(fb + (size_t)(y0c * WDIM + x0c) * CF);
        f16x8 C01 = *(const f16x8*)(fb + (size_t)(y0c * WDIM + x1c) * CF);
        f16x8 C10 = *(const f16x8*)(fb + (size_t)(y1c * WDIM + x0c) * CF);
        f16x8 C11 = *(const f16x8*)(fb + (size_t)(y1c * WDIM + x1c) * CF);

#pragma unroll
        for (int c = 0; c < 8; ++c) {
            float v =      w00 * (float)C00[c];
            v = fmaf(w01, (float)C01[c], v);
            v = fmaf(w10, (float)C10[c], v);
            v = fmaf(w11, (float)C11[c], v);
            v *= m;
            const float* w8 = wg + (k * 8 + c) * 8;
#pragma unroll
            for (int o = 0; o < 8; ++o)
                acc[o] = fmaf(w8[o], v, acc[o]);
        }
    }

    if (LAST) {
#pragma unroll
        for (int o = 0; o < 8; ++o)
            out32[((size_t)n * CF + g * 8 + o) * HW + pix] = acc[o] + bias[g * 8 + o];
    } else {
        u16 hb[8], lb[8];
#pragma unroll
        for (int o = 0; o < 8; ++o)
            split16(acc[o] + bias[g * 8 + o], hb[o], lb[o]);
        size_t b = ((size_t)n * HW + pix) * CF + g * 8;
        u32x4 hv, lv;
        hv.x = (u32)hb[0] | ((u32)hb[1] << 16); hv.y = (u32)hb[2] | ((u32)hb[3] << 16);
        hv.z = (u32)hb[4] | ((u32)hb[5] << 16); hv.w = (u32)hb[6] | ((u32)hb[7] << 16);
        lv.x = (u32)lb[0] | ((u32)lb[1] << 16); lv.y = (u32)lb[2] | ((u32)lb[3] << 16);
        lv.z = (u32)lb[4] | ((u32)lb[5] << 16); lv.w = (u32)lb[6] | ((u32)lb[7] << 16);
        *(u32x4*)(out_h + b) = hv;
        *(u32x4*)(out_l + b) = lv;
    }
}

// ---------------------------------------------------------------------------
extern "C" void kernel_launch(void* const* d_in, const int* in_sizes, int n_in,
                              void* d_out, int out_size, void* d_ws, size_t ws_size,
                              hipStream_t stream) {
    const float* burst = (const float*)d_in[0];
    const float* bw    = (const float*)d_in[1];

    const float* ow[4]; const float* dw[4]; const float* db[4];
    bool interleaved = (in_sizes[3] == 64 * 8 * 9);
    for (int i = 0; i < 4; ++i) {
        if (interleaved) {
            ow[i] = (const float*)d_in[2 + 3 * i];
            dw[i] = (const float*)d_in[3 + 3 * i];
            db[i] = (const float*)d_in[4 + 3 * i];
        } else {
            ow[i] = (const float*)d_in[2 + i];
            dw[i] = (const float*)d_in[6 + i];
            db[i] = (const float*)d_in[10 + i];
        }
    }

    float* out = (float*)d_out;

    // ws layout (74.4 MB)
    float* offs    = (float*)d_ws;                   // 10,616,832 f32 (blocked)
    u16*   mask    = (u16*)(offs + 10616832);        //  5,308,416 u16 (blocked)
    u16*   featB_h = mask + 5308416;                 //  4,718,592 u16
    u16*   featB_l = featB_h + 4718592;              //  4,718,592 u16
    u16*   wp      = featB_l + 4718592;              //  1,179,648 u16
    float* dwp     = (float*)(wp + 1179648);         //     18,432 f32
    u16*   cat_h   = (u16*)d_ws;                     // alias over offs region
    u16*   cat_l   = cat_h + 9437184;
    u16*   featA_h = (u16*)d_out;                    // alias over d_out
    u16*   featA_l = featA_h + 4718592;

    const u16* wp_bh = wp;
    const u16* wp_bl = wp + 73728;
    const u16* wp_oh[4], * wp_ol[4];
    for (int i = 0; i < 4; ++i) {
        wp_oh[i] = wp + 147456 + (size_t)i * 258048;
        wp_ol[i] = wp_oh[i] + 129024;
    }

    pack_w_k<<<dim3(512), dim3(256), 0, stream>>>(
        bw, ow[0], ow[1], ow[2], ow[3], dw[0], dw[1], dw[2], dw[3], wp, dwp);
    prep_cat_k<<<dim3(288), dim3(256), 0, stream>>>(burst, cat_h, cat_l);

    // bottleneck -> featA (d_out alias). 576 = 8 img x (36 tiles x 2 ocg)
    conv_mfma_k<128, 0><<<dim3(576), dim3(256), 0, stream>>>(
        cat_h, cat_l, wp_bh, wp_bl, nullptr, nullptr, featA_h, featA_l);

    // ping-pong: A -> B -> A -> B -> d_out(fp32)
    u16* fx_h = featA_h; u16* fx_l = featA_l;
    u16* fy_h = featB_h; u16* fy_l = featB_l;
    for (int i = 0; i < 4; ++i) {
        conv_mfma_k<64, 1><<<dim3(2016), dim3(256), 0, stream>>>(
            fx_h, fx_l, wp_oh[i], wp_ol[i], offs, mask, nullptr, nullptr);
        if (i < 3) {
            deform_k<0><<<dim3(2304), dim3(256), 0, stream>>>(
                fx_h, offs, mask, dwp + (size_t)i * 4608, db[i], fy_h, fy_l, nullptr);
            u16* th = fx_h; u16* tl = fx_l;
            fx_h = fy_h; fx_l = fy_l; fy_h = th; fy_l = tl;
        } else {
            deform_k<1><<<dim3(2304), dim3(256), 0, stream>>>(
                fx_h, offs, mask, dwp + (size_t)i * 4608, db[i], nullptr, nullptr, out);
        }
    }
}

// Round 7
// 656.933 us; speedup vs baseline: 2.0927x; 1.2517x over previous
//
#include <hip/hip_runtime.h>
#include <math.h>

#define HW    9216
#define HDIM  96
#define WDIM  96
#define NIMG  8
#define CF    64
#define OFFCH 144
#define MSKCH 72

typedef unsigned short u16;
typedef unsigned int   u32;
typedef _Float16 f16;
typedef __attribute__((ext_vector_type(8))) _Float16 f16x8;
typedef __attribute__((ext_vector_type(4))) float f32x4;
typedef __attribute__((ext_vector_type(4))) u32 u32x4;

// ---- fp16 helpers -----------------------------------------------------------
// Weights: v ~= hi + lo/2048 (lo pre-scaled x2048, kept out of subnormals).
// Activations: fp16 hi only (4.9e-4 rel — same class as the deform gather
// path which has used hi-only since round 3 with absmax pinned at the
// jax-vs-np floor 9.77e-4).
__device__ inline u16 f16b(f16 h){ u16 r; __builtin_memcpy(&r, &h, 2); return r; }
__device__ inline f16 b16f(u16 b){ f16 h; __builtin_memcpy(&h, &b, 2); return h; }
__device__ inline void split16(float v, u16& hb, u16& lb){
    f16 h = (f16)v;
    f16 l = (f16)((v - (float)h) * 2048.0f);
    hb = f16b(h); lb = f16b(l);
}

// ---- weight prepack ---------------------------------------------------------
// wp (u16): bneck hi [64*9*128] @0, lo @73728;
//           layer i: hi [224*9*64] @147456+i*258048, lo @+129024 (oc>=216 zeroed)
// dwp (f32): deform weights transposed [layer][g][k][c][o]
__global__ void pack_w_k(const float* __restrict__ bw,
                         const float* __restrict__ ow0, const float* __restrict__ ow1,
                         const float* __restrict__ ow2, const float* __restrict__ ow3,
                         const float* __restrict__ dw0, const float* __restrict__ dw1,
                         const float* __restrict__ dw2, const float* __restrict__ dw3,
                         u16* __restrict__ wp, float* __restrict__ dwp)
{
    const float* ows[4] = {ow0, ow1, ow2, ow3};
    const float* dws[4] = {dw0, dw1, dw2, dw3};
    int total = 73728 + 4 * 124416;
    for (int j = blockIdx.x * blockDim.x + threadIdx.x; j < total;
         j += gridDim.x * blockDim.x) {
        if (j < 73728) {                      // bneck src [oc][ci][tap]
            int oc = j / 1152, r = j % 1152, ci = r / 9, tap = r % 9;
            u16 h, l; split16(bw[j], h, l);
            size_t dst = (size_t)(oc * 9 + tap) * 128 + ci;
            wp[dst] = h; wp[73728 + dst] = l;
        } else {
            int k = j - 73728;
            int layer = k / 124416, r = k % 124416;
            int oc = r / 576, r3 = r % 576, ci = r3 / 9, tap = r3 % 9;
            u16 h, l; split16(ows[layer][r], h, l);
            size_t dst = 147456 + (size_t)layer * 258048 + (size_t)(oc * 9 + tap) * 64 + ci;
            wp[dst] = h; wp[dst + 129024] = l;
        }
    }
    for (int j = blockIdx.x * blockDim.x + threadIdx.x; j < 4 * 4608;
         j += gridDim.x * blockDim.x) {
        int layer = j / 4608, e = j % 4608;
        size_t base = 147456 + (size_t)layer * 258048;
        wp[base + 124416 + e] = 0;
        wp[base + 129024 + 124416 + e] = 0;
    }
    for (int j = blockIdx.x * blockDim.x + threadIdx.x; j < 4 * 8 * 576;
         j += gridDim.x * blockDim.x) {
        int layer = j / 4608, r = j % 4608, g = r / 576, e = r % 576;
        int kk = e / 64, c = (e / 8) % 8, o = e % 8;
        dwp[j] = dws[layer][(size_t)(g * 8 + o) * 72 + c * 9 + kk];
    }
}

// ---- concat(burst[n], burst[0]) -> NHWC fp16 [8][9216][128] -----------------
__global__ __launch_bounds__(256) void prep_cat_k(
    const float* __restrict__ burst, u16* __restrict__ ch)
{
    __shared__ float tb[32 * 257];
    const int id = blockIdx.x;
    const int n = id & 7, w = id >> 3;          // image-per-XCD
    const int pix0 = w * 256;
    const int tid = threadIdx.x;

    for (int pass = 0; pass < 4; ++pass) {
        const float* src = (pass < 2) ? burst + (size_t)n * CF * HW : burst;
        const int chb = (pass & 1) * 32;
        __syncthreads();
        {
            int c = tid >> 3, q = tid & 7;
            const float* sp = src + (size_t)(chb + c) * HW + pix0;
#pragma unroll
            for (int j = 0; j < 8; ++j) {
                int px = q * 4 + j * 32;
                f32x4 v = *(const f32x4*)(sp + px);
                tb[c * 257 + px + 0] = v.x;
                tb[c * 257 + px + 1] = v.y;
                tb[c * 257 + px + 2] = v.z;
                tb[c * 257 + px + 3] = v.w;
            }
        }
        __syncthreads();
        {
            int px = tid;
            size_t base = ((size_t)n * HW + pix0 + px) * 128 + pass * 32;
#pragma unroll
            for (int cq = 0; cq < 4; ++cq) {
                u32 hw_[4];
#pragma unroll
                for (int e = 0; e < 4; ++e) {
                    int c0 = cq * 8 + e * 2;
                    u16 h0 = f16b((f16)tb[c0 * 257 + px]);
                    u16 h1 = f16b((f16)tb[(c0 + 1) * 257 + px]);
                    hw_[e] = (u32)h0 | ((u32)h1 << 16);
                }
                u32x4 hv = {hw_[0], hw_[1], hw_[2], hw_[3]};
                *(u32x4*)(ch + base + cq * 8) = hv;
            }
        }
    }
}

// ---- MFMA implicit-GEMM conv3x3 (act fp16-hi; weights hi + scaled-lo) -------
// 1D grid, image-per-XCD swizzle: n=id&7, w=id>>3, tile-major (ocg fastest).
// LDS row stride 72 u16 = 144B = 9x16B -> b128 read quad = (pos + k) mod 8,
// uniform (conflict-free). Single 64-ci stage per chunk.
// MODE 0: feat NHWC fp16 out. MODE 1: tile-blocked offs fp32 + mask fp16.
template<int CIN, int MODE>
__global__ __launch_bounds__(256, 3) void conv_mfma_k(
    const u16* __restrict__ in_hi,
    const u16* __restrict__ w_hi,  const u16* __restrict__ w_lo,
    float* __restrict__ offs_out,  u16* __restrict__ mask_out,
    u16* __restrict__ out_hi)
{
    __shared__ __align__(16) u16 lds[324 * 72];     // 46656 B

    const int id = blockIdx.x;
    const int n = id & 7, w = id >> 3;
    const int tile = (MODE == 0) ? (w >> 1) : (w / 7);
    const int ocg  = (MODE == 0) ? (w & 1)  : (w % 7);
    const int tid = threadIdx.x;
    const int wv = tid >> 6, lane = tid & 63;
    const int lx = lane & 15, lg = lane >> 4;
    const int oy = (tile / 6) * 16, ox = (tile % 6) * 16;

    f32x4 acc1[2][4], acc2[2][4];
#pragma unroll
    for (int t = 0; t < 2; ++t)
#pragma unroll
        for (int r = 0; r < 4; ++r) {
            acc1[t][r] = (f32x4){0.f, 0.f, 0.f, 0.f};
            acc2[t][r] = (f32x4){0.f, 0.f, 0.f, 0.f};
        }

    for (int chk = 0; chk < CIN / 64; ++chk) {
        __syncthreads();
        // stage 18x18 halo x 64 ci (fp16 hi), 16B units
        for (int u = tid; u < 2592; u += 256) {
            int pos = u >> 3, q = u & 7;
            int yy = pos / 18, xx = pos - yy * 18;
            int gy = oy + yy - 1, gx = ox + xx - 1;
            u32x4 val = {0u, 0u, 0u, 0u};
            if (gy >= 0 && gy < HDIM && gx >= 0 && gx < WDIM)
                val = *(const u32x4*)(in_hi +
                    ((size_t)(n * HW + gy * WDIM + gx) * CIN + chk * 64 + q * 8));
            *(u32x4*)(lds + pos * 72 + q * 8) = val;
        }
        __syncthreads();

        for (int tap = 0; tap < 9; ++tap) {
            int ky = tap / 3, kx = tap - ky * 3;
            f16x8 ah[2][2], al[2][2];
#pragma unroll
            for (int t = 0; t < 2; ++t) {
                int oc = ocg * 32 + t * 16 + lx;
                size_t base = (size_t)(oc * 9 + tap) * CIN + chk * 64 + lg * 8;
                ah[t][0] = *(const f16x8*)(w_hi + base);
                ah[t][1] = *(const f16x8*)(w_hi + base + 32);
                al[t][0] = *(const f16x8*)(w_lo + base);
                al[t][1] = *(const f16x8*)(w_lo + base + 32);
            }
            f16x8 b[4][2];
#pragma unroll
            for (int r = 0; r < 4; ++r) {
                int pos = (wv * 4 + r + ky) * 18 + lx + kx;
                b[r][0] = *(const f16x8*)(lds + pos * 72 + lg * 8);
                b[r][1] = *(const f16x8*)(lds + pos * 72 + 32 + lg * 8);
            }
#pragma unroll
            for (int t = 0; t < 2; ++t)
#pragma unroll
                for (int r = 0; r < 4; ++r) {
                    acc1[t][r] = __builtin_amdgcn_mfma_f32_16x16x32_f16(ah[t][0], b[r][0], acc1[t][r], 0, 0, 0);
                    acc2[t][r] = __builtin_amdgcn_mfma_f32_16x16x32_f16(al[t][0], b[r][0], acc2[t][r], 0, 0, 0);
                    acc1[t][r] = __builtin_amdgcn_mfma_f32_16x16x32_f16(ah[t][1], b[r][1], acc1[t][r], 0, 0, 0);
                    acc2[t][r] = __builtin_amdgcn_mfma_f32_16x16x32_f16(al[t][1], b[r][1], acc2[t][r], 0, 0, 0);
                }
        }
    }

    if (MODE == 0) {
        // feat NHWC fp16 (hi only)
#pragma unroll
        for (int t = 0; t < 2; ++t)
#pragma unroll
            for (int r = 0; r < 4; ++r) {
                int y = oy + wv * 4 + r;
                int pix = y * WDIM + ox + lx;
                u16 h[4];
#pragma unroll
                for (int v = 0; v < 4; ++v) {
                    float val = acc1[t][r][v] + acc2[t][r][v] * (1.0f / 2048.0f);
                    h[v] = f16b((f16)val);
                }
                size_t b = ((size_t)(n * HW + pix)) * CF + ocg * 32 + t * 16 + lg * 4;
                uint2 hv;
                hv.x = (u32)h[0] | ((u32)h[1] << 16);
                hv.y = (u32)h[2] | ((u32)h[3] << 16);
                *(uint2*)(out_hi + b) = hv;
            }
    } else {
        // LDS-transpose epilogue -> dense tile-blocked, lane-contiguous stores
        __syncthreads();
        float* tb = (float*)lds;                 // 32 x 257 fp32 (32.9 KB)
#pragma unroll
        for (int t = 0; t < 2; ++t)
#pragma unroll
            for (int r = 0; r < 4; ++r) {
                int px = (wv * 4 + r) * 16 + lx;
#pragma unroll
                for (int v = 0; v < 4; ++v) {
                    int ocl = t * 16 + lg * 4 + v;
                    tb[ocl * 257 + px] = acc1[t][r][v] + acc2[t][r][v] * (1.0f / 2048.0f);
                }
            }
        __syncthreads();

        const int ocl = tid >> 3;                // 0..31
        const int q   = tid & 7;                 // 0..7
        const int glob = ocg * 32 + ocl;
        const float* row = tb + ocl * 257;
        if (glob < OFFCH) {
            float* dst = offs_out + (((size_t)n * 36 + tile) * OFFCH + glob) * 256;
#pragma unroll
            for (int j = 0; j < 8; ++j) {
                int px = q * 4 + j * 32;         // lanes 0..7 contiguous 128B
                f32x4 v4 = {row[px], row[px+1], row[px+2], row[px+3]};
                *(f32x4*)(dst + px) = v4;
            }
        } else if (glob < OFFCH + MSKCH) {
            u16* dst = mask_out + (((size_t)n * 36 + tile) * MSKCH + (glob - OFFCH)) * 256;
#pragma unroll
            for (int j = 0; j < 4; ++j) {
                int px = q * 8 + j * 64;         // lanes 0..7 contiguous 128B
                u32 wd[4];
#pragma unroll
                for (int e = 0; e < 4; ++e) {
                    float a = row[px + 2*e],     sa = 1.f / (1.f + __expf(-a));
                    float b = row[px + 2*e + 1], sb = 1.f / (1.f + __expf(-b));
                    wd[e] = (u32)f16b((f16)sa) | ((u32)f16b((f16)sb) << 16);
                }
                u32x4 m4 = {wd[0], wd[1], wd[2], wd[3]};
                *(u32x4*)(dst + px) = m4;
            }
        }
    }
}

// ---- modulated deformable conv; blocked offs/mask, fp16 feat gathers --------
template<int LAST>
__global__ __launch_bounds__(256, 4) void deform_k(
    const u16* __restrict__ fh,   const float* __restrict__ offs,
    const u16* __restrict__ mask, const float* __restrict__ wgtp, // [g][k][c][o]
    const float* __restrict__ bias,
    u16* __restrict__ out_h, float* __restrict__ out32)
{
    const int id = blockIdx.x;
    const int n = id & 7, w = id >> 3;
    const int tile = w >> 3, g = w & 7;          // tile-major, g fastest

    const int ty = threadIdx.x >> 4, tx = threadIdx.x & 15;
    const int h  = (tile / 6) * 16 + ty;
    const int wx = (tile % 6) * 16 + tx;
    const int pix = h * WDIM + wx;
    const int pixT = ty * 16 + tx;

    const float* wg = wgtp + (size_t)g * 576;
    const float* ob = offs + (((size_t)n * 36 + tile) * OFFCH) * 256;
    const u16*   mb = mask + (((size_t)n * 36 + tile) * MSKCH) * 256;
    const u16*   fb = fh + (size_t)n * HW * CF + g * 8;

    float acc[8];
#pragma unroll
    for (int o = 0; o < 8; ++o) acc[o] = 0.f;

#pragma unroll
    for (int k = 0; k < 9; ++k) {
        float dy = ob[(g * 18 + 2 * k    ) * 256 + pixT];
        float dx = ob[(g * 18 + 2 * k + 1) * 256 + pixT];
        float m  = (float)b16f(mb[(g * 9 + k) * 256 + pixT]);

        float py = dy + (float)(k / 3 - 1) + (float)h;
        float px = dx + (float)(k % 3 - 1) + (float)wx;
        float y0f = floorf(py), x0f = floorf(px);
        float ly = py - y0f, lx = px - x0f;
        int y0 = (int)y0f, x0 = (int)x0f;
        int y1 = y0 + 1,   x1 = x0 + 1;

        bool vy0 = (y0 >= 0) && (y0 < HDIM);
        bool vy1 = (y1 >= 0) && (y1 < HDIM);
        bool vx0 = (x0 >= 0) && (x0 < WDIM);
        bool vx1 = (x1 >= 0) && (x1 < WDIM);

        float w00 = (vy0 && vx0) ? (1.f - ly) * (1.f - lx) : 0.f;
        float w01 = (vy0 && vx1) ? (1.f - ly) * lx         : 0.f;
        float w10 = (vy1 && vx0) ? ly * (1.f - lx)         : 0.f;
        float w11 = (vy1 && vx1) ? ly * lx                 : 0.f;

        int y0c = min(max(y0, 0), HDIM - 1), y1c = min(max(y1, 0), HDIM - 1);
        int x0c = min(max(x0, 0), WDIM - 1), x1c = min(max(x1, 0), WDIM - 1);

        f16x8 C00 = *(const f16x8*)(fb + (size_t)(y0c * WDIM + x0c) * CF);
        f16x8 C01 = *(const f16x8*)(fb + (size_t)(y0c * WDIM + x1c) * CF);
        f16x8 C10 = *(const f16x8*)(fb + (size_t)(y1c * WDIM + x0c) * CF);
        f16x8 C11 = *(const f16x8*)(fb + (size_t)(y1c * WDIM + x1c) * CF);

#pragma unroll
        for (int c = 0; c < 8; ++c) {
            float v =      w00 * (float)C00[c];
            v = fmaf(w01, (float)C01[c], v);
            v = fmaf(w10, (float)C10[c], v);
            v = fmaf(w11, (float)C11[c], v);
            v *= m;
            const float* w8 = wg + (k * 8 + c) * 8;
#pragma unroll
            for (int o = 0; o < 8; ++o)
                acc[o] = fmaf(w8[o], v, acc[o]);
        }
    }

    if (LAST) {
#pragma unroll
        for (int o = 0; o < 8; ++o)
            out32[((size_t)n * CF + g * 8 + o) * HW + pix] = acc[o] + bias[g * 8 + o];
    } else {
        u16 hb[8];
#pragma unroll
        for (int o = 0; o < 8; ++o)
            hb[o] = f16b((f16)(acc[o] + bias[g * 8 + o]));
        size_t b = ((size_t)n * HW + pix) * CF + g * 8;
        u32x4 hv;
        hv.x = (u32)hb[0] | ((u32)hb[1] << 16); hv.y = (u32)hb[2] | ((u32)hb[3] << 16);
        hv.z = (u32)hb[4] | ((u32)hb[5] << 16); hv.w = (u32)hb[6] | ((u32)hb[7] << 16);
        *(u32x4*)(out_h + b) = hv;
    }
}

// ---------------------------------------------------------------------------
extern "C" void kernel_launch(void* const* d_in, const int* in_sizes, int n_in,
                              void* d_out, int out_size, void* d_ws, size_t ws_size,
                              hipStream_t stream) {
    const float* burst = (const float*)d_in[0];
    const float* bw    = (const float*)d_in[1];

    const float* ow[4]; const float* dw[4]; const float* db[4];
    bool interleaved = (in_sizes[3] == 64 * 8 * 9);
    for (int i = 0; i < 4; ++i) {
        if (interleaved) {
            ow[i] = (const float*)d_in[2 + 3 * i];
            dw[i] = (const float*)d_in[3 + 3 * i];
            db[i] = (const float*)d_in[4 + 3 * i];
        } else {
            ow[i] = (const float*)d_in[2 + i];
            dw[i] = (const float*)d_in[6 + i];
            db[i] = (const float*)d_in[10 + i];
        }
    }

    float* out = (float*)d_out;

    // ws layout (~65 MB)
    float* offs  = (float*)d_ws;                   // 10,616,832 f32 (blocked)
    u16*   mask  = (u16*)(offs + 10616832);        //  5,308,416 u16 (blocked)
    u16*   featB = mask + 5308416;                 //  4,718,592 u16
    u16*   wp    = featB + 4718592;                //  1,179,648 u16
    float* dwp   = (float*)(wp + 1179648);         //     18,432 f32
    u16*   cat_h = (u16*)d_ws;                     //  9,437,184 u16 (alias offs)
    u16*   featA = (u16*)d_out;                    //  4,718,592 u16 (alias d_out)

    const u16* wp_bh = wp;
    const u16* wp_bl = wp + 73728;
    const u16* wp_oh[4], * wp_ol[4];
    for (int i = 0; i < 4; ++i) {
        wp_oh[i] = wp + 147456 + (size_t)i * 258048;
        wp_ol[i] = wp_oh[i] + 129024;
    }

    pack_w_k<<<dim3(512), dim3(256), 0, stream>>>(
        bw, ow[0], ow[1], ow[2], ow[3], dw[0], dw[1], dw[2], dw[3], wp, dwp);
    prep_cat_k<<<dim3(288), dim3(256), 0, stream>>>(burst, cat_h);

    // bottleneck -> featA (d_out alias). 576 = 8 img x (36 tiles x 2 ocg)
    conv_mfma_k<128, 0><<<dim3(576), dim3(256), 0, stream>>>(
        cat_h, wp_bh, wp_bl, nullptr, nullptr, featA);

    // ping-pong: A -> B -> A -> B -> d_out(fp32)
    u16* fx = featA;
    u16* fy = featB;
    for (int i = 0; i < 4; ++i) {
        conv_mfma_k<64, 1><<<dim3(2016), dim3(256), 0, stream>>>(
            fx, wp_oh[i], wp_ol[i], offs, mask, nullptr);
        if (i < 3) {
            deform_k<0><<<dim3(2304), dim3(256), 0, stream>>>(
                fx, offs, mask, dwp + (size_t)i * 4608, db[i], fy, nullptr);
            u16* t = fx; fx = fy; fy = t;
        } else {
            deform_k<1><<<dim3(2304), dim3(256), 0, stream>>>(
                fx, offs, mask, dwp + (size_t)i * 4608, db[i], nullptr, out);
        }
    }
}